// Round 4
// baseline (7042.146 us; speedup 1.0000x reference)
//
#include <hip/hip_runtime.h>

// CharLSTM on MI355X — layer-pipelined persistent LSTM, round 4.
// R3 post-mortem: sc0 "fast path" = SE scope -> stale cross-CU reads -> wrong.
// R4: all exchange agent-scope sc1 (R2-proven). Operand-swapped MFMA
// (C = W x act^T) puts a full (i,f,g,o) quadruple in each lane's f32x4 ->
// no LDS, no __syncthreads in the loop; 128 WGs x 512 thr (layer x slice);
// single ring/layer (h + next-layer x unified), one drain/beat; combined
// single-observation poll for x/h/backpressure.

typedef _Float16 f16;
typedef f16  f16x8 __attribute__((ext_vector_type(8)));
typedef f16  f16x4 __attribute__((ext_vector_type(4)));
typedef float f32x4 __attribute__((ext_vector_type(4)));
typedef int   i32x4 __attribute__((ext_vector_type(4)));

#define DEV __device__ __forceinline__

constexpr int TT = 512, BB = 64, VV = 100, HH = 256, LL = 8;
constexpr int RING_D = 32;

// ---- workspace layout (bytes) ----
constexpr size_t XE_OFF = 0;
constexpr size_t XE_SZ  = (size_t)TT*BB*256*2;          // 16 MB embedded x [T][B][256] f16
constexpr size_t WP_OFF = XE_OFF + XE_SZ;
constexpr size_t WP_SZ  = (size_t)LL*16*64*512*2;       // 8 MB repacked W [L*16][64][512] f16
constexpr size_t BI_OFF = WP_OFF + WP_SZ;
constexpr size_t BI_SZ  = (size_t)LL*16*64*4;           // prescaled bias [L*16][64] f32
constexpr size_t FW_OFF = BI_OFF + BI_SZ;
constexpr size_t FW_SZ  = (size_t)112*256*2;            // fc_w padded
constexpr size_t H7_OFF = FW_OFF + FW_SZ;
constexpr size_t H7_SZ  = (size_t)TT*BB*256*2;          // 16 MB layer-7 h history
constexpr size_t RG_OFF = H7_OFF + H7_SZ;
constexpr size_t RG_SZ  = (size_t)LL*RING_D*BB*256*2;   // 8 MB rings [L][32][64][256] f16
constexpr size_t FPF_OFF = RG_OFF + RG_SZ;
constexpr size_t FPF_SZ  = (size_t)LL*TT*128;           // produced flags [L][T][sl*8+wv]
constexpr size_t FCF_OFF = FPF_OFF + FPF_SZ;
constexpr size_t FCF_SZ  = (size_t)7*TT*128;            // consumed flags [ring l][T][sl*8+wv]
constexpr size_t ONES_OFF = FCF_OFF + FCF_SZ;           // 16B of 0x01 (always-ready poll target)
constexpr int ZERO_DW = (int)((FPF_SZ + FCF_SZ) / 4);   // 245760 = 960*256

// ---- agent-scope helpers (R2-proven primitives) ----
DEV void ld16_pl (i32x4& d, const void* p){ asm volatile("global_load_dwordx4 %0, %1, off"     : "=v"(d) : "v"(p)); }
DEV void ld16_sc1(i32x4& d, const void* p){ asm volatile("global_load_dwordx4 %0, %1, off sc1" : "=v"(d) : "v"(p)); }
DEV void st2_sc1(void* p, unsigned v){ asm volatile("global_store_short %0, %1, off sc1" :: "v"(p), "v"(v) : "memory"); }
DEV void st2_pl (void* p, unsigned v){ asm volatile("global_store_short %0, %1, off"     :: "v"(p), "v"(v) : "memory"); }
DEV void stb_sc1(void* p){ unsigned o = 1; asm volatile("global_store_byte %0, %1, off sc1" :: "v"(p), "v"(o) : "memory"); }
DEV void wait_vm0(){ asm volatile("s_waitcnt vmcnt(0)" ::: "memory"); __builtin_amdgcn_sched_barrier(0); }
DEV void wait_vm8(){ asm volatile("s_waitcnt vmcnt(8)" ::: "memory"); __builtin_amdgcn_sched_barrier(0); }

// combined poll: each lane watches its role's 16B chunk; all-ready when every
// byte==0x01 across all lanes. Single observation latency for x+h+backpressure.
DEV bool pollc(const unsigned char* pa) {
  for (int it = 0; it < (1 << 19); ++it) {
    i32x4 f;
    asm volatile("global_load_dwordx4 %0, %1, off sc1\n\ts_waitcnt vmcnt(0)"
                 : "=v"(f) : "v"(pa) : "memory");
    if (__all((f[0] & f[1] & f[2] & f[3]) == 0x01010101)) return true;
    if (it > 128) __builtin_amdgcn_s_sleep(1);
  }
  return false;
}

// gates prescaled by log2e (i,f,o) and 2*log2e (g) -> raw v_exp_f32
DEV float sig2(float y)  { return __builtin_amdgcn_rcpf(1.f + __builtin_amdgcn_exp2f(-y)); }
DEV float tanhp(float y) { return 1.f - 2.f * __builtin_amdgcn_rcpf(1.f + __builtin_amdgcn_exp2f(y)); }
constexpr float LOG2E = 1.4426950408889634f;
constexpr float C2LE  = 2.8853900817779268f;
DEV unsigned f16bits(float v) { f16 h = (f16)v; return (unsigned)__builtin_bit_cast(unsigned short, h); }

// =================== prep kernels ===================
__global__ void prep_zero(unsigned int* p, unsigned int* ones) {  // grid 960x256
  p[blockIdx.x * 256 + threadIdx.x] = 0;
  if (blockIdx.x == 0 && threadIdx.x < 4) ones[threadIdx.x] = 0x01010101u;
}

__global__ void prep_embed(const int* __restrict__ x, const float* __restrict__ em,
                           f16* __restrict__ xe) {   // grid 1024x256
  int g = blockIdx.x * 256 + threadIdx.x;
  int chunk = g & 7, pair = g >> 3;
  int b = pair & 63, t = pair >> 6;
  int idx = x[b * 512 + t];
  const float* er = em + (size_t)idx * 100;
  f16* o = xe + (size_t)pair * 256 + chunk * 32;
  #pragma unroll
  for (int c4 = 0; c4 < 32; c4 += 4) {
    f16x4 v;
    #pragma unroll
    for (int q = 0; q < 4; ++q) {
      int c = chunk * 32 + c4 + q;
      v[q] = (c < 100) ? (f16)er[c] : (f16)0.f;
    }
    *(f16x4*)(o + c4) = v;
  }
}

// W row order per slice: n in [0,64): tile=n>>4, gate=n&3, unit_local=(n>>2)&3
// => MFMA C quadruple (j=0..3 -> i,f,g,o) lands per-lane. PyTorch row r=256*gate+u.
__global__ void prep_w(const float* __restrict__ w_ih0, const float* __restrict__ w_ih,
                       const float* __restrict__ w_hh, f16* __restrict__ wpo) { // grid 4096x256
  int g = blockIdx.x * 256 + threadIdx.x;
  int k4 = (g & 127) * 4;
  int n  = (g >> 7) & 63;
  int ls = g >> 13;
  int l = ls >> 4, s = ls & 15;
  int gate = n & 3;
  int u = s * 16 + ((n >> 4) << 2) + ((n >> 2) & 3);
  int r = 256 * gate + u;
  float scale = (gate == 2) ? C2LE : LOG2E;
  f16x4 v;
  #pragma unroll
  for (int q = 0; q < 4; ++q) {
    int k = k4 + q;
    float f;
    if (k < 256) {
      if (l == 0) f = (k < 100) ? w_ih0[(size_t)r * 100 + k] : 0.f;
      else        f = w_ih[((size_t)(l - 1) * 1024 + r) * 256 + k];
    } else        f = w_hh[((size_t)l * 1024 + r) * 256 + (k - 256)];
    v[q] = (f16)(f * scale);
  }
  *(f16x4*)(wpo + (size_t)g * 4) = v;
}

__global__ void prep_bias(const float* __restrict__ b_ih, const float* __restrict__ b_hh,
                          float* __restrict__ bo) {  // grid 32x256
  int g = blockIdx.x * 256 + threadIdx.x;
  int n = g & 63, s = (g >> 6) & 15, l = g >> 10;
  int gate = n & 3;
  int u = s * 16 + ((n >> 4) << 2) + ((n >> 2) & 3);
  int r = 256 * gate + u;
  float scale = (gate == 2) ? C2LE : LOG2E;
  bo[g] = (b_ih[l * 1024 + r] + b_hh[l * 1024 + r]) * scale;
}

__global__ void prep_fcw(const float* __restrict__ fc_w, f16* __restrict__ fo) { // grid 28x256
  int g = blockIdx.x * 256 + threadIdx.x;
  int n = g >> 6, k4 = (g & 63) * 4;
  f16x4 v;
  #pragma unroll
  for (int q = 0; q < 4; ++q)
    v[q] = (n < 100) ? (f16)fc_w[(size_t)n * 256 + k4 + q] : (f16)0.f;
  *(f16x4*)(fo + (size_t)g * 4) = v;
}

// =================== persistent pipeline kernel ===================
// WG(lyr = bx&7, sl = bx>>3): 64 gate-rows x 64 batch per beat, K=512.
// 8 waves: mA = wv>>2 (2 M-tiles each), nB = wv&3 (16 batch cols).
// No LDS, no barriers: waves sync only via agent-scope flags.
__global__ void __launch_bounds__(512, 2) lstm_pipe(
    const f16* __restrict__ xe, const f16* __restrict__ wp, const float* __restrict__ biasp,
    f16* h7, f16* rings, unsigned char* fpf, unsigned char* fcf,
    const unsigned char* ones, float* out)
{
  static __shared__ char pad_lds[40960];           // +41216 dyn = 82176 -> 1 WG/CU
  (void)((volatile char*)pad_lds)[threadIdx.x];

  const int bx  = blockIdx.x;
  const int lyr = bx & 7;                          // layer per XCD (perf heuristic)
  const int sl  = bx >> 3;                         // 16-unit slice
  const int tid = threadIdx.x;
  const int wv  = tid >> 6;
  const int ln  = tid & 63;
  const int mA  = wv >> 2;
  const int nB  = wv & 3;

  // ---- persistent W fragments: 2 M-tiles x 16 K-tiles (128 VGPR) ----
  f16x8 wfa[2][16];
  {
    const f16* wb = wp + (size_t)(lyr * 16 + sl) * 64 * 512;
    #pragma unroll
    for (int tt = 0; tt < 2; ++tt)
      #pragma unroll
      for (int kt = 0; kt < 16; ++kt)
        wfa[tt][kt] = *(const f16x8*)(wb + (size_t)((2 * mA + tt) * 16 + (ln & 15)) * 512
                                      + kt * 32 + (ln >> 4) * 8);
  }
  f32x4 bias_v[2];
  #pragma unroll
  for (int tt = 0; tt < 2; ++tt)
    bias_v[tt] = *(const f32x4*)(biasp + (size_t)(lyr * 16 + sl) * 64
                                 + (2 * mA + tt) * 16 + (ln >> 4) * 4);

  float cst0 = 0.f, cst1 = 0.f;                    // cell state (2 units/lane)
  const int bcol = nB * 16 + (ln & 15);            // batch col 0..63
  const int kof  = (ln >> 4) * 8;
  const f16* xring = rings + (size_t)(lyr - 1) * RING_D * 16384;  // lyr>0 only
  const f16* hring = rings + (size_t)lyr * RING_D * 16384;
  bool dead = false;

  for (int t = 0; t < TT; ++t) {
    // ---- single combined poll: x-ready | h-ready | ring backpressure ----
    if (!dead) {
      const int role = ln >> 3, chunk = (ln & 7) * 16;
      const bool nx = (lyr > 0), nh = (t > 0), nb = (lyr < 7) && (t >= RING_D);
      const unsigned char* px = fpf + (((size_t)(lyr - 1) * TT + t) << 7) + chunk;
      const unsigned char* ph = fpf + (((size_t)lyr * TT + (t - 1)) << 7) + chunk;
      const unsigned char* pb = fcf + (((size_t)lyr * TT + (t - RING_D)) << 7) + chunk;
      const unsigned char* pa;
      if (role == 1)      pa = nh ? ph : ones;
      else if (role == 2) pa = nb ? pb : ones;
      else                pa = nx ? px : (nh ? ph : ones);
      dead = !pollc(pa);
    }

    // ---- B-fragment loads: x half (kt 0..7) + h half (kt 8..15) ----
    const bool hasH = (t > 0);
    i32x4 bfx[8], bfh[8];
    {
      const f16* xb = ((lyr == 0) ? xe + (size_t)t * 16384
                                  : xring + (size_t)(t & (RING_D - 1)) * 16384)
                      + (size_t)bcol * 256 + kof;
      if (lyr == 0) {
        #pragma unroll
        for (int kt = 0; kt < 8; ++kt) ld16_pl(bfx[kt], xb + kt * 32);
      } else {
        #pragma unroll
        for (int kt = 0; kt < 8; ++kt) ld16_sc1(bfx[kt], xb + kt * 32);
      }
      if (hasH) {
        const f16* hb = hring + (size_t)((t - 1) & (RING_D - 1)) * 16384
                      + (size_t)bcol * 256 + kof;
        #pragma unroll
        for (int kt = 0; kt < 8; ++kt) ld16_sc1(bfh[kt], hb + kt * 32);
      }
    }

    // ---- MFMA: x-half under vmcnt(8), h-half after full drain ----
    f32x4 acc0 = {0,0,0,0}, acc1 = {0,0,0,0};
    if (hasH) wait_vm8(); else wait_vm0();
    #pragma unroll
    for (int kt = 0; kt < 8; ++kt) {
      f16x8 av = __builtin_bit_cast(f16x8, bfx[kt]);
      acc0 = __builtin_amdgcn_mfma_f32_16x16x32_f16(wfa[0][kt], av, acc0, 0, 0, 0);
      acc1 = __builtin_amdgcn_mfma_f32_16x16x32_f16(wfa[1][kt], av, acc1, 0, 0, 0);
    }
    if (hasH) {
      wait_vm0();
      if (lyr > 0 && ln == 0)    // x slot t consumed (loads complete)
        stb_sc1(fcf + (((size_t)(lyr - 1) * TT + t) << 7) + sl * 8 + wv);
      #pragma unroll
      for (int kt = 0; kt < 8; ++kt) {
        f16x8 av = __builtin_bit_cast(f16x8, bfh[kt]);
        acc0 = __builtin_amdgcn_mfma_f32_16x16x32_f16(wfa[0][8 + kt], av, acc0, 0, 0, 0);
        acc1 = __builtin_amdgcn_mfma_f32_16x16x32_f16(wfa[1][8 + kt], av, acc1, 0, 0, 0);
      }
    } else if (lyr > 0 && ln == 0) {
      stb_sc1(fcf + (((size_t)(lyr - 1) * TT + t) << 7) + sl * 8 + wv);
    }

    // ---- gates fully in-register: lane holds (i,f,g,o) x 2 units ----
    f16* rdst = rings + ((size_t)lyr * RING_D + (t & (RING_D - 1))) * 16384
              + (size_t)bcol * 256;
    #pragma unroll
    for (int tt = 0; tt < 2; ++tt) {
      f32x4 g4 = (tt == 0 ? acc0 : acc1);
      g4 += bias_v[tt];
      float i_ = sig2(g4[0]), f_ = sig2(g4[1]), z_ = tanhp(g4[2]), o_ = sig2(g4[3]);
      float& c_ = (tt == 0 ? cst0 : cst1);
      c_ = f_ * c_ + i_ * z_;
      float h_ = o_ * tanhp(c_ * C2LE);
      const int u = sl * 16 + (2 * mA + tt) * 4 + (ln >> 4);
      unsigned hb16 = f16bits(h_);
      st2_sc1(rdst + u, hb16);
      if (lyr == 7) st2_pl(h7 + (size_t)t * 16384 + (size_t)bcol * 256 + u, hb16);
      if (t == TT - 1) {
        size_t ob = 3276800 + (size_t)lyr * 16384 + (size_t)bcol * 256 + u;
        out[ob] = h_;  out[ob + 131072] = c_;
      }
    }
    wait_vm0();                                    // data at coherent point
    if (ln == 0)
      stb_sc1(fpf + (((size_t)lyr * TT + t) << 7) + sl * 8 + wv);
  }
}

// =================== final FC ===================
__global__ void __launch_bounds__(256, 1) fc_kernel(
    const f16* __restrict__ h7, const f16* __restrict__ fcw,
    const float* __restrict__ fcb, float* __restrict__ out)
{
  const int t  = blockIdx.x;
  const int wv = threadIdx.x >> 6;
  const int ln = threadIdx.x & 63;
  const f16* ab = h7 + (size_t)t * 16384 + (size_t)(wv * 16 + (ln & 15)) * 256 + (ln >> 4) * 8;
  f16x8 af[8];
  #pragma unroll
  for (int kt = 0; kt < 8; ++kt) af[kt] = *(const f16x8*)(ab + kt * 32);
  const int obrow = wv * 16 + (ln >> 4) * 4;
  #pragma unroll
  for (int nt = 0; nt < 7; ++nt) {
    const f16* bb = fcw + (size_t)(nt * 16 + (ln & 15)) * 256 + (ln >> 4) * 8;
    f32x4 acc = {0, 0, 0, 0};
    #pragma unroll
    for (int kt = 0; kt < 8; ++kt) {
      f16x8 bv = *(const f16x8*)(bb + kt * 32);
      acc = __builtin_amdgcn_mfma_f32_16x16x32_f16(af[kt], bv, acc, 0, 0, 0);
    }
    int vg = nt * 16 + (ln & 15);
    if (vg < VV) {
      float bias = fcb[vg];
      #pragma unroll
      for (int j = 0; j < 4; ++j)
        out[(size_t)(obrow + j) * 51200 + (size_t)t * 100 + vg] = acc[j] + bias;
    }
  }
}

// =================== launch ===================
extern "C" void kernel_launch(void* const* d_in, const int* in_sizes, int n_in,
                              void* d_out, int out_size, void* d_ws, size_t ws_size,
                              hipStream_t stream) {
  (void)in_sizes; (void)n_in; (void)out_size; (void)ws_size;
  const int*   x     = (const int*)d_in[0];
  const float* embed = (const float*)d_in[1];
  const float* w_ih0 = (const float*)d_in[2];
  const float* w_ih  = (const float*)d_in[3];
  const float* w_hh  = (const float*)d_in[4];
  const float* b_ih  = (const float*)d_in[5];
  const float* b_hh  = (const float*)d_in[6];
  const float* fc_w  = (const float*)d_in[7];
  const float* fc_b  = (const float*)d_in[8];
  char* ws = (char*)d_ws;
  float* out = (float*)d_out;

  // flags + ONES must be re-initialized every call
  prep_zero<<<960, 256, 0, stream>>>((unsigned int*)(ws + FPF_OFF),
                                     (unsigned int*)(ws + ONES_OFF));
  prep_embed<<<1024, 256, 0, stream>>>(x, embed, (f16*)(ws + XE_OFF));
  prep_w<<<4096, 256, 0, stream>>>(w_ih0, w_ih, w_hh, (f16*)(ws + WP_OFF));
  prep_bias<<<32, 256, 0, stream>>>(b_ih, b_hh, (float*)(ws + BI_OFF));
  prep_fcw<<<28, 256, 0, stream>>>(fc_w, (f16*)(ws + FW_OFF));

  // static LDS 40960 + dynamic 41216 = 82176 B > 80 KiB -> 1 WG/CU
  lstm_pipe<<<128, 512, 41216, stream>>>(
      (const f16*)(ws + XE_OFF), (const f16*)(ws + WP_OFF), (const float*)(ws + BI_OFF),
      (f16*)(ws + H7_OFF), (f16*)(ws + RG_OFF),
      (unsigned char*)(ws + FPF_OFF), (unsigned char*)(ws + FCF_OFF),
      (const unsigned char*)(ws + ONES_OFF), out);

  fc_kernel<<<512, 256, 0, stream>>>((const f16*)(ws + H7_OFF), (const f16*)(ws + FW_OFF),
                                     fc_b, out);
}

// Round 5
// 4101.272 us; speedup vs baseline: 1.7171x; 1.7171x over previous
//
#include <hip/hip_runtime.h>

// CharLSTM on MI355X — layer-pipelined persistent LSTM, round 5.
// R4 post-mortem: (a) publish was 2B scattered sc1 stores -> WRITE_SIZE 574MB,
// slow drains; (b) VGPR_Count=128 proved W fragments were NOT register-resident
// (recompiled loads every beat). R5: LDS-transpose publish (contiguous 16B
// stores by waves 0-1, 32B flag region), inline-asm register pinning of W/bias,
// earlier poll sleep. Structure otherwise R4 (swapped MFMA, in-register gates).

typedef _Float16 f16;
typedef f16  f16x8 __attribute__((ext_vector_type(8)));
typedef f16  f16x4 __attribute__((ext_vector_type(4)));
typedef float f32x4 __attribute__((ext_vector_type(4)));
typedef int   i32x4 __attribute__((ext_vector_type(4)));

#define DEV __device__ __forceinline__

constexpr int TT = 512, BB = 64, VV = 100, HH = 256, LL = 8;
constexpr int RING_D = 32;

// ---- workspace layout (bytes) ----
constexpr size_t XE_OFF = 0;
constexpr size_t XE_SZ  = (size_t)TT*BB*256*2;          // embedded x [T][B][256] f16
constexpr size_t WP_OFF = XE_OFF + XE_SZ;
constexpr size_t WP_SZ  = (size_t)LL*16*64*512*2;       // repacked W [L*16][64][512] f16
constexpr size_t BI_OFF = WP_OFF + WP_SZ;
constexpr size_t BI_SZ  = (size_t)LL*16*64*4;           // prescaled bias [L*16][64] f32
constexpr size_t FW_OFF = BI_OFF + BI_SZ;
constexpr size_t FW_SZ  = (size_t)112*256*2;            // fc_w padded
constexpr size_t H7_OFF = FW_OFF + FW_SZ;
constexpr size_t H7_SZ  = (size_t)TT*BB*256*2;          // layer-7 h history
constexpr size_t RG_OFF = H7_OFF + H7_SZ;
constexpr size_t RG_SZ  = (size_t)LL*RING_D*BB*256*2;   // rings [L][32][64][256] f16
constexpr size_t FPF_OFF = RG_OFF + RG_SZ;
constexpr size_t FPF_SZ  = (size_t)LL*TT*32;            // produced flags [L][T][sl*2+w01]
constexpr size_t FCF_OFF = FPF_OFF + FPF_SZ;
constexpr size_t FCF_SZ  = (size_t)7*TT*128;            // consumed flags [l][T][sl*8+wv]
constexpr size_t ONES_OFF = FCF_OFF + FCF_SZ;           // 16B of 0x01
constexpr int ZERO_DW = (int)((FPF_SZ + FCF_SZ) / 4);   // 147456 = 576*256

// ---- agent-scope helpers ----
DEV void ld16_pl (i32x4& d, const void* p){ asm volatile("global_load_dwordx4 %0, %1, off"     : "=v"(d) : "v"(p)); }
DEV void ld16_sc1(i32x4& d, const void* p){ asm volatile("global_load_dwordx4 %0, %1, off sc1" : "=v"(d) : "v"(p)); }
DEV void st16_sc1(void* p, i32x4 d){ asm volatile("global_store_dwordx4 %0, %1, off sc1" :: "v"(p), "v"(d) : "memory"); }
DEV void stb_sc1(void* p){ unsigned o = 1; asm volatile("global_store_byte %0, %1, off sc1" :: "v"(p), "v"(o) : "memory"); }
DEV void wait_vm0(){ asm volatile("s_waitcnt vmcnt(0)" ::: "memory"); __builtin_amdgcn_sched_barrier(0); }
DEV void wait_vm8(){ asm volatile("s_waitcnt vmcnt(8)" ::: "memory"); __builtin_amdgcn_sched_barrier(0); }

// poll: each lane watches a role-assigned 16B chunk; ready when all bytes 0x01.
DEV bool pollc(const unsigned char* pa) {
  for (int it = 0; it < (1 << 19); ++it) {
    i32x4 f;
    asm volatile("global_load_dwordx4 %0, %1, off sc1\n\ts_waitcnt vmcnt(0)"
                 : "=v"(f) : "v"(pa) : "memory");
    if (__all((f[0] & f[1] & f[2] & f[3]) == 0x01010101)) return true;
    if (it > 16) __builtin_amdgcn_s_sleep(1);
  }
  return false;
}

// gates prescaled by log2e (i,f,o) and 2*log2e (g) -> raw v_exp_f32
DEV float sig2(float y)  { return __builtin_amdgcn_rcpf(1.f + __builtin_amdgcn_exp2f(-y)); }
DEV float tanhp(float y) { return 1.f - 2.f * __builtin_amdgcn_rcpf(1.f + __builtin_amdgcn_exp2f(y)); }
constexpr float LOG2E = 1.4426950408889634f;
constexpr float C2LE  = 2.8853900817779268f;
DEV unsigned f16bits(float v) { f16 h = (f16)v; return (unsigned)__builtin_bit_cast(unsigned short, h); }

// =================== prep kernels ===================
__global__ void prep_zero(unsigned int* p, unsigned int* ones) {  // grid 576x256
  p[blockIdx.x * 256 + threadIdx.x] = 0;
  if (blockIdx.x == 0 && threadIdx.x < 4) ones[threadIdx.x] = 0x01010101u;
}

__global__ void prep_embed(const int* __restrict__ x, const float* __restrict__ em,
                           f16* __restrict__ xe) {   // grid 1024x256
  int g = blockIdx.x * 256 + threadIdx.x;
  int chunk = g & 7, pair = g >> 3;
  int b = pair & 63, t = pair >> 6;
  int idx = x[b * 512 + t];
  const float* er = em + (size_t)idx * 100;
  f16* o = xe + (size_t)pair * 256 + chunk * 32;
  #pragma unroll
  for (int c4 = 0; c4 < 32; c4 += 4) {
    f16x4 v;
    #pragma unroll
    for (int q = 0; q < 4; ++q) {
      int c = chunk * 32 + c4 + q;
      v[q] = (c < 100) ? (f16)er[c] : (f16)0.f;
    }
    *(f16x4*)(o + c4) = v;
  }
}

// W row order per slice: n in [0,64): gate=n&3, u_local=(n>>4)*4+((n>>2)&3)
__global__ void prep_w(const float* __restrict__ w_ih0, const float* __restrict__ w_ih,
                       const float* __restrict__ w_hh, f16* __restrict__ wpo) { // grid 4096x256
  int g = blockIdx.x * 256 + threadIdx.x;
  int k4 = (g & 127) * 4;
  int n  = (g >> 7) & 63;
  int ls = g >> 13;
  int l = ls >> 4, s = ls & 15;
  int gate = n & 3;
  int u = s * 16 + ((n >> 4) << 2) + ((n >> 2) & 3);
  int r = 256 * gate + u;
  float scale = (gate == 2) ? C2LE : LOG2E;
  f16x4 v;
  #pragma unroll
  for (int q = 0; q < 4; ++q) {
    int k = k4 + q;
    float f;
    if (k < 256) {
      if (l == 0) f = (k < 100) ? w_ih0[(size_t)r * 100 + k] : 0.f;
      else        f = w_ih[((size_t)(l - 1) * 1024 + r) * 256 + k];
    } else        f = w_hh[((size_t)l * 1024 + r) * 256 + (k - 256)];
    v[q] = (f16)(f * scale);
  }
  *(f16x4*)(wpo + (size_t)g * 4) = v;
}

__global__ void prep_bias(const float* __restrict__ b_ih, const float* __restrict__ b_hh,
                          float* __restrict__ bo) {  // grid 32x256
  int g = blockIdx.x * 256 + threadIdx.x;
  int n = g & 63, s = (g >> 6) & 15, l = g >> 10;
  int gate = n & 3;
  int u = s * 16 + ((n >> 4) << 2) + ((n >> 2) & 3);
  int r = 256 * gate + u;
  float scale = (gate == 2) ? C2LE : LOG2E;
  bo[g] = (b_ih[l * 1024 + r] + b_hh[l * 1024 + r]) * scale;
}

__global__ void prep_fcw(const float* __restrict__ fc_w, f16* __restrict__ fo) { // grid 28x256
  int g = blockIdx.x * 256 + threadIdx.x;
  int n = g >> 6, k4 = (g & 63) * 4;
  f16x4 v;
  #pragma unroll
  for (int q = 0; q < 4; ++q)
    v[q] = (n < 100) ? (f16)fc_w[(size_t)n * 256 + k4 + q] : (f16)0.f;
  *(f16x4*)(fo + (size_t)g * 4) = v;
}

// =================== persistent pipeline kernel ===================
// WG(lyr = bx&7, sl = bx>>3): 64 gate-rows x 64 batch per beat, K=512.
// 8 waves: mA = wv>>2 (2 M-tiles), nB = wv&3 (16 batch cols).
// Publish: gate lanes -> LDS (parity dbuf) -> barrier -> waves 0-1 store 16B/lane.
__global__ void __launch_bounds__(512, 2) lstm_pipe(
    const f16* __restrict__ xe, const f16* __restrict__ wp, const float* __restrict__ biasp,
    f16* h7, f16* rings, unsigned char* fpf, unsigned char* fcf,
    const unsigned char* ones, float* out)
{
  __shared__ char pad_lds[40960];                  // + pub 6144 + dyn 35072 = 82176 -> 1 WG/CU
  __shared__ unsigned short pub[2][64][24];        // [parity][batch][16 units + pad]
  (void)((volatile char*)pad_lds)[threadIdx.x];

  const int bx  = blockIdx.x;
  const int lyr = bx & 7;                          // layer per XCD (perf heuristic)
  const int sl  = bx >> 3;                         // 16-unit slice
  const int tid = threadIdx.x;
  const int wv  = tid >> 6;
  const int ln  = tid & 63;
  const int mA  = wv >> 2;
  const int nB  = wv & 3;

  // ---- W fragments: 2 M-tiles x 16 K-tiles, PINNED in VGPRs ----
  f16x8 wfa[2][16];
  {
    const f16* wb = wp + (size_t)(lyr * 16 + sl) * 64 * 512;
    #pragma unroll
    for (int tt = 0; tt < 2; ++tt)
      #pragma unroll
      for (int kt = 0; kt < 16; ++kt) {
        wfa[tt][kt] = *(const f16x8*)(wb + (size_t)((2 * mA + tt) * 16 + (ln & 15)) * 512
                                      + kt * 32 + (ln >> 4) * 8);
        i32x4 pin = __builtin_bit_cast(i32x4, wfa[tt][kt]);
        asm volatile("" : "+v"(pin));              // forbid re-load inside loop
        wfa[tt][kt] = __builtin_bit_cast(f16x8, pin);
      }
  }
  f32x4 bias_v[2];
  #pragma unroll
  for (int tt = 0; tt < 2; ++tt) {
    bias_v[tt] = *(const f32x4*)(biasp + (size_t)(lyr * 16 + sl) * 64
                                 + (2 * mA + tt) * 16 + (ln >> 4) * 4);
    asm volatile("" : "+v"(bias_v[tt]));
  }

  float cst0 = 0.f, cst1 = 0.f;                    // cell state (2 units/lane)
  const int q    = ln >> 4;                        // 0..3
  const int bcol = nB * 16 + (ln & 15);            // batch col 0..63
  const int kof  = q * 8;
  const f16* xring = rings + (size_t)(lyr - 1) * RING_D * 16384;
  f16*       hring = rings + (size_t)lyr * RING_D * 16384;
  bool dead = false;

  for (int t = 0; t < TT; ++t) {
    // ---- combined poll: x-ready | h-ready | ring backpressure ----
    if (!dead) {
      const int r = ln & 15;
      const bool nx = (lyr > 0), nh = (t > 0), nb = (lyr < 7) && (t >= RING_D);
      const unsigned char* px = fpf + (size_t)((lyr - 1) * TT + t) * 32;
      const unsigned char* ph = fpf + (size_t)(lyr * TT + (t - 1)) * 32;
      const unsigned char* pb = fcf + (((size_t)lyr * TT + (t - RING_D)) << 7);
      const unsigned char* pa;
      if (r < 2)       pa = nx ? px + r * 16 : (nh ? ph + r * 16 : ones);
      else if (r < 4)  pa = nh ? ph + (r - 2) * 16 : ones;
      else if (r < 12) pa = nb ? pb + (r - 4) * 16 : ones;
      else             pa = nh ? ph + (r & 1) * 16 : (nx ? px + (r & 1) * 16 : ones);
      dead = !pollc(pa);
    }

    // ---- B-fragment loads: x half then h half ----
    const bool hasH = (t > 0);
    i32x4 bfx[8], bfh[8];
    {
      const f16* xb = ((lyr == 0) ? xe + (size_t)t * 16384
                                  : xring + (size_t)(t & (RING_D - 1)) * 16384)
                      + (size_t)bcol * 256 + kof;
      if (lyr == 0) {
        #pragma unroll
        for (int kt = 0; kt < 8; ++kt) ld16_pl(bfx[kt], xb + kt * 32);
      } else {
        #pragma unroll
        for (int kt = 0; kt < 8; ++kt) ld16_sc1(bfx[kt], xb + kt * 32);
      }
      if (hasH) {
        const f16* hb = hring + (size_t)((t - 1) & (RING_D - 1)) * 16384
                      + (size_t)bcol * 256 + kof;
        #pragma unroll
        for (int kt = 0; kt < 8; ++kt) ld16_sc1(bfh[kt], hb + kt * 32);
      }
    }

    // ---- MFMA: x-half under vmcnt(8); x-consumed flag; h-half after drain ----
    f32x4 acc0 = {0,0,0,0}, acc1 = {0,0,0,0};
    if (hasH) wait_vm8(); else wait_vm0();
    if (lyr > 0 && ln == 0)      // x slot t consumed (x loads retired)
      stb_sc1(fcf + (((size_t)(lyr - 1) * TT + t) << 7) + sl * 8 + wv);
    #pragma unroll
    for (int kt = 0; kt < 8; ++kt) {
      f16x8 av = __builtin_bit_cast(f16x8, bfx[kt]);
      acc0 = __builtin_amdgcn_mfma_f32_16x16x32_f16(wfa[0][kt], av, acc0, 0, 0, 0);
      acc1 = __builtin_amdgcn_mfma_f32_16x16x32_f16(wfa[1][kt], av, acc1, 0, 0, 0);
    }
    if (hasH) {
      wait_vm0();
      #pragma unroll
      for (int kt = 0; kt < 8; ++kt) {
        f16x8 av = __builtin_bit_cast(f16x8, bfh[kt]);
        acc0 = __builtin_amdgcn_mfma_f32_16x16x32_f16(wfa[0][8 + kt], av, acc0, 0, 0, 0);
        acc1 = __builtin_amdgcn_mfma_f32_16x16x32_f16(wfa[1][8 + kt], av, acc1, 0, 0, 0);
      }
    }

    // ---- gates in-register; h -> LDS transpose buffer ----
    const int par = t & 1;
    #pragma unroll
    for (int tt = 0; tt < 2; ++tt) {
      f32x4 g4 = (tt == 0 ? acc0 : acc1);
      g4 += bias_v[tt];
      float i_ = sig2(g4[0]), f_ = sig2(g4[1]), z_ = tanhp(g4[2]), o_ = sig2(g4[3]);
      float& c_ = (tt == 0 ? cst0 : cst1);
      c_ = f_ * c_ + i_ * z_;
      float h_ = o_ * tanhp(c_ * C2LE);
      pub[par][bcol][(2 * mA + tt) * 4 + q] = (unsigned short)f16bits(h_);
      if (t == TT - 1) {
        const int u = sl * 16 + (2 * mA + tt) * 4 + q;
        size_t ob = 3276800 + (size_t)lyr * 16384 + (size_t)bcol * 256 + u;
        out[ob] = h_;  out[ob + 131072] = c_;
      }
    }
    __syncthreads();                               // single barrier per beat

    // ---- publish: waves 0-1, contiguous 16B/lane, then flag ----
    if (wv < 2) {
      const int idx = wv * 64 + ln;                // 0..127
      const int b = idx >> 1, half = idx & 1;
      i32x4 d = *(const i32x4*)&pub[par][b][half * 8];
      f16* dst = hring + (size_t)(t & (RING_D - 1)) * 16384
               + (size_t)b * 256 + sl * 16 + half * 8;
      st16_sc1(dst, d);
      if (lyr == 7)
        *(i32x4*)(h7 + (size_t)t * 16384 + (size_t)b * 256 + sl * 16 + half * 8) = d;
      wait_vm0();
      if (ln == 0)
        stb_sc1(fpf + (size_t)(lyr * TT + t) * 32 + sl * 2 + wv);
    }
  }
}

// =================== final FC ===================
__global__ void __launch_bounds__(256, 1) fc_kernel(
    const f16* __restrict__ h7, const f16* __restrict__ fcw,
    const float* __restrict__ fcb, float* __restrict__ out)
{
  const int t  = blockIdx.x;
  const int wv = threadIdx.x >> 6;
  const int ln = threadIdx.x & 63;
  const f16* ab = h7 + (size_t)t * 16384 + (size_t)(wv * 16 + (ln & 15)) * 256 + (ln >> 4) * 8;
  f16x8 af[8];
  #pragma unroll
  for (int kt = 0; kt < 8; ++kt) af[kt] = *(const f16x8*)(ab + kt * 32);
  const int obrow = wv * 16 + (ln >> 4) * 4;
  #pragma unroll
  for (int nt = 0; nt < 7; ++nt) {
    const f16* bb = fcw + (size_t)(nt * 16 + (ln & 15)) * 256 + (ln >> 4) * 8;
    f32x4 acc = {0, 0, 0, 0};
    #pragma unroll
    for (int kt = 0; kt < 8; ++kt) {
      f16x8 bv = *(const f16x8*)(bb + kt * 32);
      acc = __builtin_amdgcn_mfma_f32_16x16x32_f16(af[kt], bv, acc, 0, 0, 0);
    }
    int vg = nt * 16 + (ln & 15);
    if (vg < VV) {
      float bias = fcb[vg];
      #pragma unroll
      for (int j = 0; j < 4; ++j)
        out[(size_t)(obrow + j) * 51200 + (size_t)t * 100 + vg] = acc[j] + bias;
    }
  }
}

// =================== launch ===================
extern "C" void kernel_launch(void* const* d_in, const int* in_sizes, int n_in,
                              void* d_out, int out_size, void* d_ws, size_t ws_size,
                              hipStream_t stream) {
  (void)in_sizes; (void)n_in; (void)out_size; (void)ws_size;
  const int*   x     = (const int*)d_in[0];
  const float* embed = (const float*)d_in[1];
  const float* w_ih0 = (const float*)d_in[2];
  const float* w_ih  = (const float*)d_in[3];
  const float* w_hh  = (const float*)d_in[4];
  const float* b_ih  = (const float*)d_in[5];
  const float* b_hh  = (const float*)d_in[6];
  const float* fc_w  = (const float*)d_in[7];
  const float* fc_b  = (const float*)d_in[8];
  char* ws = (char*)d_ws;
  float* out = (float*)d_out;

  // flags + ONES must be re-initialized every call
  prep_zero<<<576, 256, 0, stream>>>((unsigned int*)(ws + FPF_OFF),
                                     (unsigned int*)(ws + ONES_OFF));
  prep_embed<<<1024, 256, 0, stream>>>(x, embed, (f16*)(ws + XE_OFF));
  prep_w<<<4096, 256, 0, stream>>>(w_ih0, w_ih, w_hh, (f16*)(ws + WP_OFF));
  prep_bias<<<32, 256, 0, stream>>>(b_ih, b_hh, (float*)(ws + BI_OFF));
  prep_fcw<<<28, 256, 0, stream>>>(fc_w, (f16*)(ws + FW_OFF));

  // static LDS 47104 + dynamic 35072 = 82176 B > 80 KiB -> 1 WG/CU
  lstm_pipe<<<128, 512, 35072, stream>>>(
      (const f16*)(ws + XE_OFF), (const f16*)(ws + WP_OFF), (const float*)(ws + BI_OFF),
      (f16*)(ws + H7_OFF), (f16*)(ws + RG_OFF),
      (unsigned char*)(ws + FPF_OFF), (unsigned char*)(ws + FCF_OFF),
      (const unsigned char*)(ws + ONES_OFF), out);

  fc_kernel<<<512, 256, 0, stream>>>((const f16*)(ws + H7_OFF), (const f16*)(ws + FW_OFF),
                                     fc_b, out);
}

// Round 6
// 2948.410 us; speedup vs baseline: 2.3885x; 1.3910x over previous
//
#include <hip/hip_runtime.h>

// CharLSTM on MI355X — layer-pipelined persistent LSTM, round 6.
// R5 post-mortem: beat ~8us vs ~1.5us hop-model; all-lane all-wave device-scope
// polling of a few hot flag lines contended the MALL (and caused 45ms outliers).
// R6: wave0-only poll (3 predicated lanes, 16B flag lines = 1 byte/WG),
// wave0-only publish with single drain + 2 flag bytes per WG-beat,
// launch_bounds(512,1). Structure otherwise R5 (swapped MFMA, in-reg gates,
// LDS transpose publish, unified ring).

typedef _Float16 f16;
typedef f16  f16x8 __attribute__((ext_vector_type(8)));
typedef f16  f16x4 __attribute__((ext_vector_type(4)));
typedef float f32x4 __attribute__((ext_vector_type(4)));
typedef int   i32x4 __attribute__((ext_vector_type(4)));

#define DEV __device__ __forceinline__

constexpr int TT = 512, BB = 64, VV = 100, HH = 256, LL = 8;
constexpr int RING_D = 32;

// ---- workspace layout (bytes) ----
constexpr size_t XE_OFF = 0;
constexpr size_t XE_SZ  = (size_t)TT*BB*256*2;          // embedded x [T][B][256] f16
constexpr size_t WP_OFF = XE_OFF + XE_SZ;
constexpr size_t WP_SZ  = (size_t)LL*16*64*512*2;       // repacked W [L*16][64][512] f16
constexpr size_t BI_OFF = WP_OFF + WP_SZ;
constexpr size_t BI_SZ  = (size_t)LL*16*64*4;           // prescaled bias [L*16][64] f32
constexpr size_t FW_OFF = BI_OFF + BI_SZ;
constexpr size_t FW_SZ  = (size_t)112*256*2;            // fc_w padded
constexpr size_t H7_OFF = FW_OFF + FW_SZ;
constexpr size_t H7_SZ  = (size_t)TT*BB*256*2;          // layer-7 h history
constexpr size_t RG_OFF = H7_OFF + H7_SZ;
constexpr size_t RG_SZ  = (size_t)LL*RING_D*BB*256*2;   // rings [L][32][64][256] f16
constexpr size_t FPF_OFF = RG_OFF + RG_SZ;
constexpr size_t FPF_SZ  = (size_t)LL*TT*16;            // produced flags [L][T][sl] 1B/WG
constexpr size_t FCF_OFF = FPF_OFF + FPF_SZ;
constexpr size_t FCF_SZ  = (size_t)7*TT*16;             // consumed flags [l][T][sl] 1B/WG
constexpr int ZERO_DW = (int)((FPF_SZ + FCF_SZ) / 4);   // 30720 = 120*256

// ---- agent-scope helpers ----
DEV void ld16_pl (i32x4& d, const void* p){ asm volatile("global_load_dwordx4 %0, %1, off"     : "=v"(d) : "v"(p)); }
DEV void ld16_sc1(i32x4& d, const void* p){ asm volatile("global_load_dwordx4 %0, %1, off sc1" : "=v"(d) : "v"(p)); }
DEV void st16_sc1(void* p, i32x4 d){ asm volatile("global_store_dwordx4 %0, %1, off sc1" :: "v"(p), "v"(d) : "memory"); }
DEV void stb_sc1(void* p){ unsigned o = 1; asm volatile("global_store_byte %0, %1, off sc1" :: "v"(p), "v"(o) : "memory"); }
DEV void wait_vm0(){ asm volatile("s_waitcnt vmcnt(0)" ::: "memory"); __builtin_amdgcn_sched_barrier(0); }
DEV void wait_vm8(){ asm volatile("s_waitcnt vmcnt(8)" ::: "memory"); __builtin_amdgcn_sched_barrier(0); }

// wave0-only poll: lane0 watches h-line, lane1 x-line, lane2 backpressure-line
// (each a 16B line, one byte per producer/consumer WG). nullptr = not needed.
DEV bool pollw0(const unsigned char* ph, const unsigned char* px,
                const unsigned char* pc, int ln) {
  const unsigned char* pa = (ln == 0) ? ph : (ln == 1) ? px : (ln == 2) ? pc : nullptr;
  for (int it = 0; it < (1 << 16); ++it) {
    bool ok = true;
    if (pa) {
      i32x4 f;
      asm volatile("global_load_dwordx4 %0, %1, off sc1\n\ts_waitcnt vmcnt(0)"
                   : "=v"(f) : "v"(pa) : "memory");
      ok = ((f[0] & f[1] & f[2] & f[3]) == 0x01010101);
    }
    if (__all(ok)) return true;
  }
  return false;
}

// gates prescaled by log2e (i,f,o) and 2*log2e (g) -> raw v_exp_f32
DEV float sig2(float y)  { return __builtin_amdgcn_rcpf(1.f + __builtin_amdgcn_exp2f(-y)); }
DEV float tanhp(float y) { return 1.f - 2.f * __builtin_amdgcn_rcpf(1.f + __builtin_amdgcn_exp2f(y)); }
constexpr float LOG2E = 1.4426950408889634f;
constexpr float C2LE  = 2.8853900817779268f;
DEV unsigned f16bits(float v) { f16 h = (f16)v; return (unsigned)__builtin_bit_cast(unsigned short, h); }

// =================== prep kernels ===================
__global__ void prep_zero(unsigned int* p) {  // grid 120x256 == 30720 dwords exactly
  p[blockIdx.x * 256 + threadIdx.x] = 0;
}

__global__ void prep_embed(const int* __restrict__ x, const float* __restrict__ em,
                           f16* __restrict__ xe) {   // grid 1024x256
  int g = blockIdx.x * 256 + threadIdx.x;
  int chunk = g & 7, pair = g >> 3;
  int b = pair & 63, t = pair >> 6;
  int idx = x[b * 512 + t];
  const float* er = em + (size_t)idx * 100;
  f16* o = xe + (size_t)pair * 256 + chunk * 32;
  #pragma unroll
  for (int c4 = 0; c4 < 32; c4 += 4) {
    f16x4 v;
    #pragma unroll
    for (int q = 0; q < 4; ++q) {
      int c = chunk * 32 + c4 + q;
      v[q] = (c < 100) ? (f16)er[c] : (f16)0.f;
    }
    *(f16x4*)(o + c4) = v;
  }
}

// W row order per slice: n in [0,64): gate=n&3, u_local=(n>>4)*4+((n>>2)&3)
__global__ void prep_w(const float* __restrict__ w_ih0, const float* __restrict__ w_ih,
                       const float* __restrict__ w_hh, f16* __restrict__ wpo) { // grid 4096x256
  int g = blockIdx.x * 256 + threadIdx.x;
  int k4 = (g & 127) * 4;
  int n  = (g >> 7) & 63;
  int ls = g >> 13;
  int l = ls >> 4, s = ls & 15;
  int gate = n & 3;
  int u = s * 16 + ((n >> 4) << 2) + ((n >> 2) & 3);
  int r = 256 * gate + u;
  float scale = (gate == 2) ? C2LE : LOG2E;
  f16x4 v;
  #pragma unroll
  for (int q = 0; q < 4; ++q) {
    int k = k4 + q;
    float f;
    if (k < 256) {
      if (l == 0) f = (k < 100) ? w_ih0[(size_t)r * 100 + k] : 0.f;
      else        f = w_ih[((size_t)(l - 1) * 1024 + r) * 256 + k];
    } else        f = w_hh[((size_t)l * 1024 + r) * 256 + (k - 256)];
    v[q] = (f16)(f * scale);
  }
  *(f16x4*)(wpo + (size_t)g * 4) = v;
}

__global__ void prep_bias(const float* __restrict__ b_ih, const float* __restrict__ b_hh,
                          float* __restrict__ bo) {  // grid 32x256
  int g = blockIdx.x * 256 + threadIdx.x;
  int n = g & 63, s = (g >> 6) & 15, l = g >> 10;
  int gate = n & 3;
  int u = s * 16 + ((n >> 4) << 2) + ((n >> 2) & 3);
  int r = 256 * gate + u;
  float scale = (gate == 2) ? C2LE : LOG2E;
  bo[g] = (b_ih[l * 1024 + r] + b_hh[l * 1024 + r]) * scale;
}

__global__ void prep_fcw(const float* __restrict__ fc_w, f16* __restrict__ fo) { // grid 28x256
  int g = blockIdx.x * 256 + threadIdx.x;
  int n = g >> 6, k4 = (g & 63) * 4;
  f16x4 v;
  #pragma unroll
  for (int q = 0; q < 4; ++q)
    v[q] = (n < 100) ? (f16)fc_w[(size_t)n * 256 + k4 + q] : (f16)0.f;
  *(f16x4*)(fo + (size_t)g * 4) = v;
}

// =================== persistent pipeline kernel ===================
// WG(lyr = bx&7, sl = bx>>3): 64 gate-rows x 64 batch per beat, K=512.
// 8 waves: mA = wv>>2 (2 M-tiles), nB = wv&3 (16 batch cols).
// Beat: [wave0 polls, barrier] -> loads+MFMA+gates -> LDS pub -> barrier ->
//       wave0 publishes (2KB contiguous), 1 drain, 2 flag bytes.
__global__ void __launch_bounds__(512, 1) lstm_pipe(
    const f16* __restrict__ xe, const f16* __restrict__ wp, const float* __restrict__ biasp,
    f16* h7, f16* rings, unsigned char* fpf, unsigned char* fcf, float* out)
{
  __shared__ char pad_lds[40960];                  // + pub 6144 + dyn 35072 = 82176 -> 1 WG/CU
  __shared__ unsigned short pub[2][64][24];        // [parity][batch][16 units + pad]
  (void)((volatile char*)pad_lds)[threadIdx.x];

  const int bx  = blockIdx.x;
  const int lyr = bx & 7;                          // layer per XCD (perf heuristic)
  const int sl  = bx >> 3;                         // 16-unit slice
  const int tid = threadIdx.x;
  const int wv  = tid >> 6;
  const int ln  = tid & 63;
  const int mA  = wv >> 2;
  const int nB  = wv & 3;

  // ---- W fragments: 2 M-tiles x 16 K-tiles, register-resident ----
  f16x8 wfa[2][16];
  {
    const f16* wb = wp + (size_t)(lyr * 16 + sl) * 64 * 512;
    #pragma unroll
    for (int tt = 0; tt < 2; ++tt)
      #pragma unroll
      for (int kt = 0; kt < 16; ++kt) {
        wfa[tt][kt] = *(const f16x8*)(wb + (size_t)((2 * mA + tt) * 16 + (ln & 15)) * 512
                                      + kt * 32 + (ln >> 4) * 8);
        i32x4 pin = __builtin_bit_cast(i32x4, wfa[tt][kt]);
        asm volatile("" : "+v"(pin));              // freeze: no re-load inside loop
        wfa[tt][kt] = __builtin_bit_cast(f16x8, pin);
      }
  }
  f32x4 bias_v[2];
  #pragma unroll
  for (int tt = 0; tt < 2; ++tt) {
    bias_v[tt] = *(const f32x4*)(biasp + (size_t)(lyr * 16 + sl) * 64
                                 + (2 * mA + tt) * 16 + (ln >> 4) * 4);
    asm volatile("" : "+v"(bias_v[tt]));
  }

  float cst0 = 0.f, cst1 = 0.f;                    // cell state (2 units/lane)
  const int q    = ln >> 4;                        // 0..3
  const int bcol = nB * 16 + (ln & 15);            // batch col 0..63
  const int kof  = q * 8;
  const f16* xring = rings + (size_t)(lyr - 1) * RING_D * 16384;
  f16*       hring = rings + (size_t)lyr * RING_D * 16384;
  bool dead = false;

  for (int t = 0; t < TT; ++t) {
    // ---- wave0 polls: h(t-1) ready | x(t) ready | ring slot free ----
    if (wv == 0 && !dead) {
      const unsigned char* ph = (t > 0)   ? fpf + (size_t)(lyr * TT + (t - 1)) * 16 : nullptr;
      const unsigned char* px = (lyr > 0) ? fpf + (size_t)((lyr - 1) * TT + t) * 16 : nullptr;
      const unsigned char* pc = (lyr < 7 && t >= RING_D)
                                ? fcf + (size_t)(lyr * TT + (t - RING_D)) * 16 : nullptr;
      dead = !pollw0(ph, px, pc, ln);
    }
    __syncthreads();                               // barrier #1: release all waves

    // ---- B-fragment loads: x half then h half ----
    const bool hasH = (t > 0);
    i32x4 bfx[8], bfh[8];
    {
      const f16* xb = ((lyr == 0) ? xe + (size_t)t * 16384
                                  : xring + (size_t)(t & (RING_D - 1)) * 16384)
                      + (size_t)bcol * 256 + kof;
      if (lyr == 0) {
        #pragma unroll
        for (int kt = 0; kt < 8; ++kt) ld16_pl(bfx[kt], xb + kt * 32);
      } else {
        #pragma unroll
        for (int kt = 0; kt < 8; ++kt) ld16_sc1(bfx[kt], xb + kt * 32);
      }
      if (hasH) {
        const f16* hb = hring + (size_t)((t - 1) & (RING_D - 1)) * 16384
                      + (size_t)bcol * 256 + kof;
        #pragma unroll
        for (int kt = 0; kt < 8; ++kt) ld16_sc1(bfh[kt], hb + kt * 32);
      }
    }

    // ---- MFMA: x-half under vmcnt(8); h-half after full drain ----
    f32x4 acc0 = {0,0,0,0}, acc1 = {0,0,0,0};
    if (hasH) wait_vm8(); else wait_vm0();
    #pragma unroll
    for (int kt = 0; kt < 8; ++kt) {
      f16x8 av = __builtin_bit_cast(f16x8, bfx[kt]);
      acc0 = __builtin_amdgcn_mfma_f32_16x16x32_f16(wfa[0][kt], av, acc0, 0, 0, 0);
      acc1 = __builtin_amdgcn_mfma_f32_16x16x32_f16(wfa[1][kt], av, acc1, 0, 0, 0);
    }
    if (hasH) {
      wait_vm0();
      #pragma unroll
      for (int kt = 0; kt < 8; ++kt) {
        f16x8 av = __builtin_bit_cast(f16x8, bfh[kt]);
        acc0 = __builtin_amdgcn_mfma_f32_16x16x32_f16(wfa[0][8 + kt], av, acc0, 0, 0, 0);
        acc1 = __builtin_amdgcn_mfma_f32_16x16x32_f16(wfa[1][8 + kt], av, acc1, 0, 0, 0);
      }
    }

    // ---- gates in-register; h -> LDS transpose buffer ----
    const int par = t & 1;
    #pragma unroll
    for (int tt = 0; tt < 2; ++tt) {
      f32x4 g4 = (tt == 0 ? acc0 : acc1);
      g4 += bias_v[tt];
      float i_ = sig2(g4[0]), f_ = sig2(g4[1]), z_ = tanhp(g4[2]), o_ = sig2(g4[3]);
      float& c_ = (tt == 0 ? cst0 : cst1);
      c_ = f_ * c_ + i_ * z_;
      float h_ = o_ * tanhp(c_ * C2LE);
      pub[par][bcol][(2 * mA + tt) * 4 + q] = (unsigned short)f16bits(h_);
      if (t == TT - 1) {
        const int u = sl * 16 + (2 * mA + tt) * 4 + q;
        size_t ob = 3276800 + (size_t)lyr * 16384 + (size_t)bcol * 256 + u;
        out[ob] = h_;  out[ob + 131072] = c_;
      }
    }
    __syncthreads();                               // barrier #2

    // ---- publish: wave 0 only, 32B/lane contiguous, 1 drain, 2 flag bytes ----
    if (wv == 0) {
      i32x4 d0 = *(const i32x4*)&pub[par][ln][0];
      i32x4 d1 = *(const i32x4*)&pub[par][ln][8];
      f16* dst = hring + (size_t)(t & (RING_D - 1)) * 16384 + (size_t)ln * 256 + sl * 16;
      st16_sc1(dst, d0);
      st16_sc1(dst + 8, d1);
      if (lyr == 7) {
        f16* hd = h7 + (size_t)t * 16384 + (size_t)ln * 256 + sl * 16;
        *(i32x4*)hd = d0;
        *(i32x4*)(hd + 8) = d1;
      }
      wait_vm0();                                  // data at coherent point
      if (ln == 0) stb_sc1(fpf + (size_t)(lyr * TT + t) * 16 + sl);
      if (ln == 1 && lyr > 0)                      // x slot t consumed (loads retired)
        stb_sc1(fcf + (size_t)((lyr - 1) * TT + t) * 16 + sl);
    }
  }
}

// =================== final FC ===================
__global__ void __launch_bounds__(256, 1) fc_kernel(
    const f16* __restrict__ h7, const f16* __restrict__ fcw,
    const float* __restrict__ fcb, float* __restrict__ out)
{
  const int t  = blockIdx.x;
  const int wv = threadIdx.x >> 6;
  const int ln = threadIdx.x & 63;
  const f16* ab = h7 + (size_t)t * 16384 + (size_t)(wv * 16 + (ln & 15)) * 256 + (ln >> 4) * 8;
  f16x8 af[8];
  #pragma unroll
  for (int kt = 0; kt < 8; ++kt) af[kt] = *(const f16x8*)(ab + kt * 32);
  const int obrow = wv * 16 + (ln >> 4) * 4;
  #pragma unroll
  for (int nt = 0; nt < 7; ++nt) {
    const f16* bb = fcw + (size_t)(nt * 16 + (ln & 15)) * 256 + (ln >> 4) * 8;
    f32x4 acc = {0, 0, 0, 0};
    #pragma unroll
    for (int kt = 0; kt < 8; ++kt) {
      f16x8 bv = *(const f16x8*)(bb + kt * 32);
      acc = __builtin_amdgcn_mfma_f32_16x16x32_f16(af[kt], bv, acc, 0, 0, 0);
    }
    int vg = nt * 16 + (ln & 15);
    if (vg < VV) {
      float bias = fcb[vg];
      #pragma unroll
      for (int j = 0; j < 4; ++j)
        out[(size_t)(obrow + j) * 51200 + (size_t)t * 100 + vg] = acc[j] + bias;
    }
  }
}

// =================== launch ===================
extern "C" void kernel_launch(void* const* d_in, const int* in_sizes, int n_in,
                              void* d_out, int out_size, void* d_ws, size_t ws_size,
                              hipStream_t stream) {
  (void)in_sizes; (void)n_in; (void)out_size; (void)ws_size;
  const int*   x     = (const int*)d_in[0];
  const float* embed = (const float*)d_in[1];
  const float* w_ih0 = (const float*)d_in[2];
  const float* w_ih  = (const float*)d_in[3];
  const float* w_hh  = (const float*)d_in[4];
  const float* b_ih  = (const float*)d_in[5];
  const float* b_hh  = (const float*)d_in[6];
  const float* fc_w  = (const float*)d_in[7];
  const float* fc_b  = (const float*)d_in[8];
  char* ws = (char*)d_ws;
  float* out = (float*)d_out;

  // flags must be re-zeroed every call
  prep_zero<<<120, 256, 0, stream>>>((unsigned int*)(ws + FPF_OFF));
  prep_embed<<<1024, 256, 0, stream>>>(x, embed, (f16*)(ws + XE_OFF));
  prep_w<<<4096, 256, 0, stream>>>(w_ih0, w_ih, w_hh, (f16*)(ws + WP_OFF));
  prep_bias<<<32, 256, 0, stream>>>(b_ih, b_hh, (float*)(ws + BI_OFF));
  prep_fcw<<<28, 256, 0, stream>>>(fc_w, (f16*)(ws + FW_OFF));

  // static LDS 47104 + dynamic 35072 = 82176 B > 80 KiB -> 1 WG/CU
  lstm_pipe<<<128, 512, 35072, stream>>>(
      (const f16*)(ws + XE_OFF), (const f16*)(ws + WP_OFF), (const float*)(ws + BI_OFF),
      (f16*)(ws + H7_OFF), (f16*)(ws + RG_OFF),
      (unsigned char*)(ws + FPF_OFF), (unsigned char*)(ws + FCF_OFF), out);

  fc_kernel<<<512, 256, 0, stream>>>((const f16*)(ws + H7_OFF), (const f16*)(ws + FW_OFF),
                                     fc_b, out);
}